// Round 10
// baseline (333.548 us; speedup 1.0000x reference)
//
#include <hip/hip_runtime.h>
#include <hip/hip_bf16.h>

// Problem constants (SymNetDP): B=64, S=4096, NGB=13, NG=48, DIM=3, NCH={8,8,1}
#define BATCH 64
#define SITES 4096
#define NGB 13
#define NGRP 48
#define SDIM 3

#define LOG2E 1.44269504f
#define SPSCALE 0.014440236f   // ln2/48: converts log2-domain softplus sum

typedef __bf16 bf16x8 __attribute__((ext_vector_type(8)));
typedef float  f32x4  __attribute__((ext_vector_type(4)));

// ---------------------------------------------------------------------------
// Workspace layout:
//   Avc  : 39 f32 (pad 64)                      @ float 0
//   U    : bf16 region, 135168 elems            @ float 64
//     W0H [384][32] 12288 | W0L @12288 | W1H [384][128] @24576 (49152) |
//     W1L @73728 | W2H [48][128] @122880 (6144) | W2L @129024
//   A0   : (B,S,8) channel-last f32             @ float 67648
//   SW   : [3][4096] f32, ALIASES A0 (A0 dead once L1 done)
//   A1   : (B,S,8) channel-last f32             @ float 2164800
//   PART : (512,3) f32 partials                 @ float 4261952
// K-packing for NCIN=8 layers: k = j*8 + c  (site's 8 channels contiguous).
//
// v20 = v19 + (a) L2 producer/consumer wave split, (b) bias in acc init.
// (a) L2 was staging-latency-bound at 2 waves/SIMD (256 thr, SPT=4, tiny
//     MFMA/epilogue). Now 512 thr: waves 0-3 compute chunk c, waves 4-7
//     stage chunk c+1 concurrently -> chunk time = max(stage, compute),
//     occupancy 4 waves/SIMD. Legal because the FUSED tail is linear (each
//     wave's partial sums merge in the block reduction).
// (b) acc init = bias*log2e instead of 0 (+bo per eval deleted) - bias is
//     added once per K-chain either way.
// ---------------------------------------------------------------------------
#define OFF_AVC  0
#define OFF_U    64
#define OFF_A0   67648
#define OFF_SW   67648
#define OFF_A1   2164800
#define OFF_PART 4261952
#define UW0H 0
#define UW0L 12288
#define UW1H 24576
#define UW1L 73728
#define UW2H 122880
#define UW2L 129024

// ---------------------------------------------------------------------------
// Precompute: rotated weights scaled by log2e, bf16 hi/lo split,
// [row=o*48+g][KPAD] with k=j*8+c packing for K=104 layers (k=j for L0);
// plus Avc (true units - vector channel is linear, no softplus).
// ---------------------------------------------------------------------------
__global__ __launch_bounds__(256) void precompute_kernel(
    const float* __restrict__ Psi0, const float* __restrict__ Psi1,
    const float* __restrict__ Psi2, const float* __restrict__ wtVC,
    const float* __restrict__ gdiags, const int* __restrict__ perms,
    float* __restrict__ ws)
{
    float*  Avc = ws + OFF_AVC;
    __bf16* U   = (__bf16*)(ws + OFF_U);
    int t = blockIdx.x * 256 + threadIdx.x;
    if (t < 12288) {                       // W0: [384][32], k=j
        int k = t & 31, row = t >> 5;
        int o = row / NGRP, g = row - o * NGRP;
        float w = (k < NGB) ? Psi0[o * NGB + perms[g * NGB + k]] * LOG2E : 0.f;
        __bf16 hi = (__bf16)w;
        U[UW0H + t] = hi;
        U[UW0L + t] = (__bf16)(w - (float)hi);
    } else if (t < 61440) {                // W1: [384][128], k=j*8+c
        int u = t - 12288;
        int k = u & 127, row = u >> 7;
        int o = row / NGRP, g = row - o * NGRP;
        float w = 0.f;
        if (k < 104) { int j = k >> 3, c = k & 7;
                       w = Psi1[(o * 8 + c) * NGB + perms[g * NGB + j]] * LOG2E; }
        __bf16 hi = (__bf16)w;
        U[UW1H + u] = hi;
        U[UW1L + u] = (__bf16)(w - (float)hi);
    } else if (t < 67584) {                // W2: [48][128], k=j*8+c
        int u = t - 61440;
        int k = u & 127, g = u >> 7;
        float w = 0.f;
        if (k < 104) { int j = k >> 3, c = k & 7;
                       w = Psi2[c * NGB + perms[g * NGB + j]] * LOG2E; }
        __bf16 hi = (__bf16)w;
        U[UW2H + u] = hi;
        U[UW2L + u] = (__bf16)(w - (float)hi);
    } else if (t < 67584 + 39 * NGRP) {    // Avc (true units)
        int t2 = t - 67584;
        int g = t2 % NGRP, u = t2 / NGRP;
        int d = u / NGB, n = u % NGB;
        const int row = g * SDIM + d;
        float s = 0.f;
        for (int k = 0; k < NGRP * SDIM; k++) {
            int g2 = k / SDIM, d2 = k - g2 * SDIM;
            float p = wtVC[d2 * NGB + perms[g2 * NGB + n]];
            s = fmaf(gdiags[row * (NGRP * SDIM) + k], p, s);
        }
        atomicAdd(&Avc[u], s * (1.f / 48.f));
    }
}

// ---------------------------------------------------------------------------
// build_sw: SW[d][t] = sum over edges (n,s) with NN[n,s]=t of
//   Avc[d,n] * ShellW[S2Sh[s]] * (ln2/48) / SITES.
// ---------------------------------------------------------------------------
__global__ __launch_bounds__(256) void build_sw(
    const float* __restrict__ Avc, const int* __restrict__ NN,
    const int* __restrict__ s2sh, const float* __restrict__ shellw,
    float* __restrict__ SW)
{
    int e = blockIdx.x * 256 + threadIdx.x;    // e = n*SITES + s
    if (e < NGB * SITES) {
        int n = e / SITES, s = e - n * SITES;
        float wgt = shellw[s2sh[s]] * (SPSCALE / (float)SITES);
        int t = NN[e];
        atomicAdd(&SW[t],             Avc[n] * wgt);
        atomicAdd(&SW[SITES + t],     Avc[NGB + n] * wgt);
        atomicAdd(&SW[2 * SITES + t], Avc[2 * NGB + n] * wgt);
    }
}

// ---------------------------------------------------------------------------
// MFMA gconv layer (bf16x3 split).
// SPLIT==0: v13/v19 structure (all waves compute, stage late).
// SPLIT==1: waves [0,NWAVES/2) compute; waves [NWAVES/2,NWAVES) stage the
//           next chunk concurrently. Requires FUSED (linear tail).
// Epilogue: log2-domain softplus, bias pre-folded into acc init.
// ---------------------------------------------------------------------------
template<int NCIN, int NCTOT, int CT, int KPAD, int KSTR, int NWAVES, int NWN,
         int CHUNKS, int FUSED, int SPLIT>
__global__ __launch_bounds__(NWAVES * 64) void layer_mfma(
    const float* __restrict__ prev,   // (B,S) if NCIN==1 else (B,S,8)
    const __bf16* __restrict__ Wh,    // [NCTOT*48][KPAD]
    const __bf16* __restrict__ Wl,
    const float* __restrict__ bias,   // (NCTOT,)
    const int*   __restrict__ NN,     // (13, S)
    const float* __restrict__ SWp,    // [3][SITES] (FUSED only)
    float* __restrict__ partial,      // (grid,3)   (FUSED only)
    float* __restrict__ out)          // (B,S,NCTOT) channel-last (!FUSED)
{
    constexpr int NTHR   = NWAVES * 64;
    constexpr int NWC    = SPLIT ? NWAVES / 2 : NWAVES;  // compute waves
    constexpr int M      = NCTOT * NGRP;
    constexpr int MTILES = M / 16, NTILES = CT / 16;
    constexpr int NWM    = NWC / NWN;
    constexpr int MT_W   = MTILES / NWM, NT_W = NTILES / NWN;
    constexpr int KT     = KPAD / 32;
    constexpr int GS     = NGB * CT;              // gathered sites per chunk
    constexpr int SPT    = (GS + NTHR - 1) / NTHR;
    constexpr int PTHR   = SPLIT ? NTHR / 2 : NTHR;
    constexpr int SPT_P  = (GS + PTHR - 1) / PTHR;
    constexpr int CPB    = SITES / CT;            // chunks per batch
    constexpr int BUF    = CT * KSTR;             // halfwords per LDS buffer
    constexpr int BPB    = CPB / CHUNKS;          // blocks per batch

    static_assert(MT_W * 16 == NGRP, "wave covers exactly one o");
    static_assert(NWM * MT_W == MTILES && NWN * NT_W == NTILES, "");
    static_assert((KPAD & 31) == 0 && (KSTR & 7) == 0, "");
    static_assert(CPB % CHUNKS == 0, "block stays within one batch");
    static_assert(!SPLIT || FUSED, "split needs linear tail");

    __shared__ __bf16 xh_lds[2 * BUF];
    __shared__ __bf16 xl_lds[2 * BUF];

    const int tid  = threadIdx.x;
    const int wave = tid >> 6, lane = tid & 63;
    const int m16  = lane & 15, quad = lane >> 4;

    const int bid    = blockIdx.x;
    const int b      = bid / BPB;
    const int octet  = bid % BPB;
    const int s0base = octet * (CHUNKS * CT);

    // staging of one site (slot col/j given): load -> split -> LDS write
    auto stage_to = [&](int col, int j, int nn, __bf16* dh, __bf16* dl) {
        if constexpr (NCIN == 1) {
            float v = prev[(size_t)b * SITES + nn];
            __bf16 hi = (__bf16)v;
            dh[col * KSTR + j] = hi;
            dl[col * KSTR + j] = (__bf16)(v - (float)hi);
        } else {
            const float4* p4 = (const float4*)(prev + ((size_t)(b * SITES + nn)) * 8);
            float4 u0 = p4[0], u1 = p4[1];
            float v[8] = {u0.x, u0.y, u0.z, u0.w, u1.x, u1.y, u1.z, u1.w};
            bf16x8 hv, lv;
#pragma unroll
            for (int c8 = 0; c8 < 8; c8++) {
                __bf16 hi = (__bf16)v[c8];
                hv[c8] = hi;
                lv[c8] = (__bf16)(v[c8] - (float)hi);
            }
            *(bf16x8*)(dh + col * KSTR + j * 8) = hv;
            *(bf16x8*)(dl + col * KSTR + j * 8) = lv;
        }
    };

    // --- zero the K-pad region of BOTH buffers once -------------------------
    if constexpr (NCIN == 1) {
        for (int e = tid; e < 2 * CT * (KPAD - NGB); e += NTHR) {
            int buf = e / (CT * (KPAD - NGB));
            int r   = e % (CT * (KPAD - NGB));
            int col = r / (KPAD - NGB), p = r % (KPAD - NGB);
            xh_lds[buf * BUF + col * KSTR + NGB + p] = (__bf16)0.f;
            xl_lds[buf * BUF + col * KSTR + NGB + p] = (__bf16)0.f;
        }
    } else {
        const bf16x8 z8 = {};
        for (int e = tid; e < 2 * CT * 3; e += NTHR) {
            int buf = e / (CT * 3);
            int r   = e % (CT * 3);
            int col = r % CT, z = r / CT;
            *(bf16x8*)(xh_lds + buf * BUF + col * KSTR + 104 + z * 8) = z8;
            *(bf16x8*)(xl_lds + buf * BUF + col * KSTR + 104 + z * 8) = z8;
        }
    }

    // --- prologue: ALL threads stage chunk 0 into buffer 0 ------------------
#pragma unroll
    for (int i = 0; i < SPT; i++) {
        int site = tid + i * NTHR;
        if (site < GS) {
            int j = site / CT, col = site % CT;
            int nn = NN[j * SITES + s0base + col];
            stage_to(col, j, nn, xh_lds, xl_lds);
        }
    }

    // slot decomposition + NN prefetch for the steady-state stager set
    int pj[SPT_P], pcol[SPT_P], nnP[SPT_P];
    bool pv[SPT_P];
    {
        const int tid2 = SPLIT ? (tid - NWC * 64) : tid;   // stager-local id
        const bool is_stager = SPLIT ? (wave >= NWC) : true;
#pragma unroll
        for (int i = 0; i < SPT_P; i++) {
            int site = tid2 + i * PTHR;
            pv[i] = is_stager && site >= 0 && site < GS;
            int ss = (site >= 0 && site < GS) ? site : 0;
            pj[i] = ss / CT;
            pcol[i] = ss % CT;
        }
        if (CHUNKS > 1) {
            const int s1 = s0base + CT;
#pragma unroll
            for (int i = 0; i < SPT_P; i++)
                nnP[i] = pv[i] ? NN[pj[i] * SITES + s1 + pcol[i]] : 0;
        }
    }
    __syncthreads();

    const int wave_mt0 = ((wave % NWC) / NWN) * MT_W;
    const int wave_nt0 = ((wave % NWC) % NWN) * NT_W;
    const int o_g      = (wave_mt0 * 16) / NGRP;
    const float bo     = bias[o_g] * LOG2E;

    float y0 = 0.f, y1 = 0.f, y2 = 0.f;   // FUSED accumulators

#pragma unroll 1
    for (int c = 0; c < CHUNKS; c++) {
        const int cur = c & 1;
        const __bf16* xh = xh_lds + cur * BUF;
        const __bf16* xl = xl_lds + cur * BUF;
        __bf16* dh = xh_lds + (cur ^ 1) * BUF;
        __bf16* dl = xl_lds + (cur ^ 1) * BUF;

        if (!SPLIT || wave < NWC) {
            // --- compute chunk c from buffer cur (bias in acc init) ---------
            f32x4 acc[MT_W][NT_W];
            const f32x4 binit = {bo, bo, bo, bo};
#pragma unroll
            for (int mt = 0; mt < MT_W; mt++)
#pragma unroll
                for (int nt = 0; nt < NT_W; nt++) acc[mt][nt] = binit;

#pragma unroll
            for (int kt = 0; kt < KT; kt++) {
                const int koff = kt * 32 + quad * 8;
                bf16x8 ah[MT_W], al[MT_W], bh[NT_W], bl[NT_W];
#pragma unroll
                for (int mt = 0; mt < MT_W; mt++) {
                    int row = (wave_mt0 + mt) * 16 + m16;
                    ah[mt] = *(const bf16x8*)(Wh + (size_t)row * KPAD + koff);
                    al[mt] = *(const bf16x8*)(Wl + (size_t)row * KPAD + koff);
                }
#pragma unroll
                for (int nt = 0; nt < NT_W; nt++) {
                    int cbase = ((wave_nt0 + nt) * 16 + m16) * KSTR + koff;
                    bh[nt] = *(const bf16x8*)(xh + cbase);
                    bl[nt] = *(const bf16x8*)(xl + cbase);
                }
                // product-major: independent MFMAs between same-acc reuse
#pragma unroll
                for (int mt = 0; mt < MT_W; mt++)
#pragma unroll
                    for (int nt = 0; nt < NT_W; nt++)
                        acc[mt][nt] = __builtin_amdgcn_mfma_f32_16x16x32_bf16(
                            ah[mt], bh[nt], acc[mt][nt], 0, 0, 0);
#pragma unroll
                for (int mt = 0; mt < MT_W; mt++)
#pragma unroll
                    for (int nt = 0; nt < NT_W; nt++)
                        acc[mt][nt] = __builtin_amdgcn_mfma_f32_16x16x32_bf16(
                            al[mt], bh[nt], acc[mt][nt], 0, 0, 0);
#pragma unroll
                for (int mt = 0; mt < MT_W; mt++)
#pragma unroll
                    for (int nt = 0; nt < NT_W; nt++)
                        acc[mt][nt] = __builtin_amdgcn_mfma_f32_16x16x32_bf16(
                            ah[mt], bl[nt], acc[mt][nt], 0, 0, 0);
            }

            // --- epilogue: log2-domain softplus + group mean ----------------
            const int s0c = s0base + c * CT;
#pragma unroll
            for (int nt = 0; nt < NT_W; nt++) {
                float s = 0.f;
#pragma unroll
                for (int mt = 0; mt < MT_W; mt++)
#pragma unroll
                    for (int r = 0; r < 4; r++) {
                        float h = acc[mt][nt][r];
                        s += fmaxf(h, 0.f) + __log2f(1.f + exp2f(-fabsf(h)));
                    }
                s += __shfl_xor(s, 16);
                s += __shfl_xor(s, 32);
                if (quad == 0) {
                    int site = s0c + (wave_nt0 + nt) * 16 + m16;
                    if constexpr (FUSED) {
                        y0 = fmaf(SWp[site],             s, y0);
                        y1 = fmaf(SWp[SITES + site],     s, y1);
                        y2 = fmaf(SWp[2 * SITES + site], s, y2);
                    } else {
                        out[((size_t)(b * SITES + site)) * NCTOT + o_g] = s * SPSCALE;
                    }
                }
            }
        }

        // --- stage chunk c+1 into buffer cur^1 ------------------------------
        // SPLIT: stager waves run this concurrently with the compute above.
        // !SPLIT: all waves run it after their epilogue (v13 ordering).
        if (c + 1 < CHUNKS) {
            if (!SPLIT || wave >= NWC) {
#pragma unroll
                for (int i = 0; i < SPT_P; i++) if (pv[i])
                    stage_to(pcol[i], pj[i], nnP[i], dh, dl);
                if (c + 2 < CHUNKS) {
                    const int s2 = s0base + (c + 2) * CT;
#pragma unroll
                    for (int i = 0; i < SPT_P; i++)
                        nnP[i] = pv[i] ? NN[pj[i] * SITES + s2 + pcol[i]] : 0;
                }
            }
        }
        __syncthreads();
    }

    // --- FUSED: block-reduce y[3] -> per-block partial ----------------------
    if constexpr (FUSED) {
        float* red = (float*)xh_lds;   // last loop iter ended with a barrier
        red[tid] = y0;
        red[NTHR + tid] = y1;
        red[2 * NTHR + tid] = y2;
        __syncthreads();
        for (int st = NTHR / 2; st > 0; st >>= 1) {
            if (tid < st) {
                red[tid] += red[tid + st];
                red[NTHR + tid] += red[NTHR + tid + st];
                red[2 * NTHR + tid] += red[2 * NTHR + tid + st];
            }
            __syncthreads();
        }
        if (tid < 3) partial[bid * 3 + tid] = red[tid * NTHR];
    }
}

// ---------------------------------------------------------------------------
// final_sum: out[b,d] = sum over the batch's 8 octet blocks (deterministic).
// ---------------------------------------------------------------------------
__global__ __launch_bounds__(256) void final_sum(
    const float* __restrict__ partial, float* __restrict__ out)
{
    int t = threadIdx.x;
    if (t < BATCH * 3) {
        int b = t / 3, d = t - b * 3;
        float s = 0.f;
        for (int o = 0; o < 8; o++) s += partial[(b * 8 + o) * 3 + d];
        out[t] = s;
    }
}

// ---------------------------------------------------------------------------
extern "C" void kernel_launch(void* const* d_in, const int* in_sizes, int n_in,
                              void* d_out, int out_size, void* d_ws, size_t ws_size,
                              hipStream_t stream)
{
    const float* InStates = (const float*)d_in[0];
    const float* Psi0     = (const float*)d_in[1];
    const float* bias0    = (const float*)d_in[2];
    const float* Psi1     = (const float*)d_in[3];
    const float* bias1    = (const float*)d_in[4];
    const float* Psi2     = (const float*)d_in[5];
    const float* bias2    = (const float*)d_in[6];
    const float* wtVC     = (const float*)d_in[7];
    const float* ShellW   = (const float*)d_in[8];
    const float* gdiags   = (const float*)d_in[9];
    const int*   GnnPerms = (const int*)d_in[10];
    const int*   NNSites  = (const int*)d_in[11];
    const int*   S2Sh     = (const int*)d_in[12];

    float*  ws   = (float*)d_ws;
    float*  Avc  = ws + OFF_AVC;
    __bf16* U    = (__bf16*)(ws + OFF_U);
    float*  A0   = ws + OFF_A0;      // (B,S,8) channel-last
    float*  SW   = ws + OFF_SW;      // [3][4096], aliases A0 (dead after L1)
    float*  A1   = ws + OFF_A1;      // (B,S,8) channel-last
    float*  PART = ws + OFF_PART;    // (512,3)

    float* out = (float*)d_out;      // (64,3) f32

    hipMemsetAsync(Avc, 0, 64 * sizeof(float), stream);
    precompute_kernel<<<272, 256, 0, stream>>>(Psi0, Psi1, Psi2, wtVC, gdiags,
                                               GnnPerms, ws);

    constexpr int CHUNKS = 8;
    constexpr int NBLK   = BATCH * (SITES / 64) / CHUNKS;   // 512 blocks

    // L0: K=13 pad 32, KSTR=40
    layer_mfma<1, 8, 64, 32, 40, 8, 1, CHUNKS, 0, 0><<<NBLK, 512, 0, stream>>>(
        InStates, U + UW0H, U + UW0L, bias0, NNSites, nullptr, nullptr, A0);
    // L1: K=104 pad 128, KSTR=136
    layer_mfma<8, 8, 64, 128, 136, 8, 1, CHUNKS, 0, 0><<<NBLK, 512, 0, stream>>>(
        A0, U + UW1H, U + UW1L, bias1, NNSites, nullptr, nullptr, A1);

    // SW build (stream-ordered after L1: A0 region is dead)
    hipMemsetAsync(SW, 0, 3 * SITES * sizeof(float), stream);
    build_sw<<<(NGB * SITES + 255) / 256, 256, 0, stream>>>(
        Avc, NNSites, S2Sh, ShellW, SW);

    // L2: 8 waves = 4 compute (NWN=4) + 4 stagers; fused SW tail
    layer_mfma<8, 1, 64, 128, 136, 8, 4, CHUNKS, 1, 1><<<NBLK, 512, 0, stream>>>(
        A1, U + UW2H, U + UW2L, bias2, NNSites, SW, PART, nullptr);

    final_sum<<<1, 256, 0, stream>>>(PART, out);
}

// Round 11
// 310.315 us; speedup vs baseline: 1.0749x; 1.0749x over previous
//
#include <hip/hip_runtime.h>
#include <hip/hip_bf16.h>

// Problem constants (SymNetDP): B=64, S=4096, NGB=13, NG=48, DIM=3, NCH={8,8,1}
#define BATCH 64
#define SITES 4096
#define NGB 13
#define NGRP 48
#define SDIM 3

#define LOG2E 1.44269504f
#define SPSCALE 0.014440236f   // ln2/48: converts log2-domain softplus sum

typedef __bf16 bf16x8 __attribute__((ext_vector_type(8)));
typedef float  f32x4  __attribute__((ext_vector_type(4)));

// ---------------------------------------------------------------------------
// Workspace layout:
//   Avc  : 39 f32 (pad 64)                      @ float 0
//   U    : bf16 region, 135168 elems            @ float 64
//     W0H [384][32] 12288 | W0L @12288 | W1H [384][128] @24576 (49152) |
//     W1L @73728 | W2H [48][128] @122880 (6144) | W2L @129024
//   A0   : (B,S,8) channel-last f32             @ float 67648
//   SW   : [3][4096] f32, ALIASES A0 (A0 dead once L1 done)
//   A1   : (B,S,8) channel-last f32             @ float 2164800
//   PART : (512,3) f32 partials                 @ float 4261952
// K-packing for NCIN=8 layers: k = j*8 + c  (site's 8 channels contiguous).
//
// v21 = v19 (champion, 310.6us) + LDS k-extent diet.
// v20 post-mortem: L2 producer/consumer wave split +23us (barrier coupled
// stagers to computers per block, killing cross-block interleave) ->
// reverted to v19's unified 256-thr L2. Kept bias-in-acc-init (neutral,
// fewer insts).
// LDS diet: NCIN==8 layers store k-extent 104 only (KSTR=104, no zero-pad
// region). kt=3 B-frag offsets clamp to 96 for quads 1-3 (broadcast read of
// quad-0's data); the weight table is zero for k>=104 so A=0 annihilates B.
// LDS/block 69632 -> 53248 B: L2 (256 thr, LDS-capped) goes 2 -> 3
// blocks/CU (+50% TLP on the latency-bound straggler); pad-zero prologue
// and 3/4 of kt-3 B-traffic deleted.
// ---------------------------------------------------------------------------
#define OFF_AVC  0
#define OFF_U    64
#define OFF_A0   67648
#define OFF_SW   67648
#define OFF_A1   2164800
#define OFF_PART 4261952
#define UW0H 0
#define UW0L 12288
#define UW1H 24576
#define UW1L 73728
#define UW2H 122880
#define UW2L 129024

// ---------------------------------------------------------------------------
// Precompute: rotated weights scaled by log2e, bf16 hi/lo split,
// [row=o*48+g][KPAD] with k=j*8+c packing for K=104 layers (k=j for L0);
// plus Avc (true units - vector channel is linear, no softplus).
// ---------------------------------------------------------------------------
__global__ __launch_bounds__(256) void precompute_kernel(
    const float* __restrict__ Psi0, const float* __restrict__ Psi1,
    const float* __restrict__ Psi2, const float* __restrict__ wtVC,
    const float* __restrict__ gdiags, const int* __restrict__ perms,
    float* __restrict__ ws)
{
    float*  Avc = ws + OFF_AVC;
    __bf16* U   = (__bf16*)(ws + OFF_U);
    int t = blockIdx.x * 256 + threadIdx.x;
    if (t < 12288) {                       // W0: [384][32], k=j
        int k = t & 31, row = t >> 5;
        int o = row / NGRP, g = row - o * NGRP;
        float w = (k < NGB) ? Psi0[o * NGB + perms[g * NGB + k]] * LOG2E : 0.f;
        __bf16 hi = (__bf16)w;
        U[UW0H + t] = hi;
        U[UW0L + t] = (__bf16)(w - (float)hi);
    } else if (t < 61440) {                // W1: [384][128], k=j*8+c
        int u = t - 12288;
        int k = u & 127, row = u >> 7;
        int o = row / NGRP, g = row - o * NGRP;
        float w = 0.f;
        if (k < 104) { int j = k >> 3, c = k & 7;
                       w = Psi1[(o * 8 + c) * NGB + perms[g * NGB + j]] * LOG2E; }
        __bf16 hi = (__bf16)w;
        U[UW1H + u] = hi;
        U[UW1L + u] = (__bf16)(w - (float)hi);
    } else if (t < 67584) {                // W2: [48][128], k=j*8+c
        int u = t - 61440;
        int k = u & 127, g = u >> 7;
        float w = 0.f;
        if (k < 104) { int j = k >> 3, c = k & 7;
                       w = Psi2[c * NGB + perms[g * NGB + j]] * LOG2E; }
        __bf16 hi = (__bf16)w;
        U[UW2H + u] = hi;
        U[UW2L + u] = (__bf16)(w - (float)hi);
    } else if (t < 67584 + 39 * NGRP) {    // Avc (true units)
        int t2 = t - 67584;
        int g = t2 % NGRP, u = t2 / NGRP;
        int d = u / NGB, n = u % NGB;
        const int row = g * SDIM + d;
        float s = 0.f;
        for (int k = 0; k < NGRP * SDIM; k++) {
            int g2 = k / SDIM, d2 = k - g2 * SDIM;
            float p = wtVC[d2 * NGB + perms[g2 * NGB + n]];
            s = fmaf(gdiags[row * (NGRP * SDIM) + k], p, s);
        }
        atomicAdd(&Avc[u], s * (1.f / 48.f));
    }
}

// ---------------------------------------------------------------------------
// build_sw: SW[d][t] = sum over edges (n,s) with NN[n,s]=t of
//   Avc[d,n] * ShellW[S2Sh[s]] * (ln2/48) / SITES.
// ---------------------------------------------------------------------------
__global__ __launch_bounds__(256) void build_sw(
    const float* __restrict__ Avc, const int* __restrict__ NN,
    const int* __restrict__ s2sh, const float* __restrict__ shellw,
    float* __restrict__ SW)
{
    int e = blockIdx.x * 256 + threadIdx.x;    // e = n*SITES + s
    if (e < NGB * SITES) {
        int n = e / SITES, s = e - n * SITES;
        float wgt = shellw[s2sh[s]] * (SPSCALE / (float)SITES);
        int t = NN[e];
        atomicAdd(&SW[t],             Avc[n] * wgt);
        atomicAdd(&SW[SITES + t],     Avc[NGB + n] * wgt);
        atomicAdd(&SW[2 * SITES + t], Avc[2 * NGB + n] * wgt);
    }
}

// ---------------------------------------------------------------------------
// MFMA gconv layer (bf16x3 split), v19 structure + KEXT diet.
// Persistent-lite: per iteration compute chunk c from buffer c&1, epilogue,
// THEN gather+convert+ds_write chunk c+1 (indices prefetched; only nnA ints
// cross the compute phase). Product-major MFMA order.
// KEXT < KPAD (NCIN==8): LDS holds k in [0,KEXT) only; B-frag offsets clamp
// to KEXT-8 (weights are zero for k>=KEXT -> A=0 annihilates the clamped B).
// Epilogue: log2-domain softplus, bias pre-folded into acc init.
// FUSED (L2): y[3] += SW[d][site]*sraw; per-block partial at kernel end.
// ---------------------------------------------------------------------------
template<int NCIN, int NCTOT, int CT, int KPAD, int KEXT, int KSTR,
         int NWAVES, int NWN, int CHUNKS, int FUSED>
__global__ __launch_bounds__(NWAVES * 64) void layer_mfma(
    const float* __restrict__ prev,   // (B,S) if NCIN==1 else (B,S,8)
    const __bf16* __restrict__ Wh,    // [NCTOT*48][KPAD]
    const __bf16* __restrict__ Wl,
    const float* __restrict__ bias,   // (NCTOT,)
    const int*   __restrict__ NN,     // (13, S)
    const float* __restrict__ SWp,    // [3][SITES] (FUSED only)
    float* __restrict__ partial,      // (grid,3)   (FUSED only)
    float* __restrict__ out)          // (B,S,NCTOT) channel-last (!FUSED)
{
    constexpr int NTHR   = NWAVES * 64;
    constexpr int M      = NCTOT * NGRP;
    constexpr int MTILES = M / 16, NTILES = CT / 16;
    constexpr int NWM    = NWAVES / NWN;
    constexpr int MT_W   = MTILES / NWM, NT_W = NTILES / NWN;
    constexpr int KT     = KPAD / 32;
    constexpr int GS     = NGB * CT;              // gathered sites per chunk
    constexpr int SPT    = (GS + NTHR - 1) / NTHR;
    constexpr int CPB    = SITES / CT;            // chunks per batch
    constexpr int BUF    = CT * KSTR;             // halfwords per LDS buffer
    constexpr int BPB    = CPB / CHUNKS;          // blocks per batch

    static_assert(MT_W * 16 == NGRP, "wave covers exactly one o");
    static_assert(NWM * MT_W == MTILES && NWN * NT_W == NTILES, "");
    static_assert((KPAD & 31) == 0 && (KSTR & 7) == 0, "");
    static_assert(KEXT <= KPAD && (KEXT & 7) == 0 && KSTR >= KEXT, "");
    static_assert(CPB % CHUNKS == 0, "block stays within one batch");

    __shared__ __bf16 xh_lds[2 * BUF];
    __shared__ __bf16 xl_lds[2 * BUF];

    const int tid  = threadIdx.x;
    const int wave = tid >> 6, lane = tid & 63;
    const int m16  = lane & 15, quad = lane >> 4;

    const int bid    = blockIdx.x;
    const int b      = bid / BPB;
    const int octet  = bid % BPB;
    const int s0base = octet * (CHUNKS * CT);

    // --- per-thread staged-site slots (static decomposition) ----------------
    int sj[SPT], scol[SPT];
    bool sv[SPT];
#pragma unroll
    for (int i = 0; i < SPT; i++) {
        int site = tid + i * NTHR;
        sv[i] = (site < GS);
        int ss = sv[i] ? site : 0;
        sj[i] = ss / CT;
        scol[i] = ss % CT;
    }

    // staging of one site: load -> hi/lo split -> LDS write (consumed at once)
    auto stage_site = [&](int i, int nn, __bf16* dh, __bf16* dl) {
        if constexpr (NCIN == 1) {
            float v = prev[(size_t)b * SITES + nn];
            __bf16 hi = (__bf16)v;
            dh[scol[i] * KSTR + sj[i]] = hi;
            dl[scol[i] * KSTR + sj[i]] = (__bf16)(v - (float)hi);
        } else {
            const float4* p4 = (const float4*)(prev + ((size_t)(b * SITES + nn)) * 8);
            float4 u0 = p4[0], u1 = p4[1];
            float v[8] = {u0.x, u0.y, u0.z, u0.w, u1.x, u1.y, u1.z, u1.w};
            bf16x8 hv, lv;
#pragma unroll
            for (int c8 = 0; c8 < 8; c8++) {
                __bf16 hi = (__bf16)v[c8];
                hv[c8] = hi;
                lv[c8] = (__bf16)(v[c8] - (float)hi);
            }
            *(bf16x8*)(dh + scol[i] * KSTR + sj[i] * 8) = hv;
            *(bf16x8*)(dl + scol[i] * KSTR + sj[i] * 8) = lv;
        }
    };

    // --- zero K-pad (NCIN==1 only; NCIN==8 has no pad region: KEXT=13*8) ----
    if constexpr (NCIN == 1) {
        for (int e = tid; e < 2 * CT * (KPAD - NGB); e += NTHR) {
            int buf = e / (CT * (KPAD - NGB));
            int r   = e % (CT * (KPAD - NGB));
            int col = r / (KPAD - NGB), p = r % (KPAD - NGB);
            xh_lds[buf * BUF + col * KSTR + NGB + p] = (__bf16)0.f;
            xl_lds[buf * BUF + col * KSTR + NGB + p] = (__bf16)0.f;
        }
    }

    // --- prologue: stage chunk 0 into buffer 0; prefetch NN for chunk 1 -----
    int nnA[SPT];
#pragma unroll
    for (int i = 0; i < SPT; i++) if (sv[i]) {
        int nn = NN[sj[i] * SITES + s0base + scol[i]];
        stage_site(i, nn, xh_lds, xl_lds);
    }
    if (CHUNKS > 1) {
        const int s1 = s0base + CT;
#pragma unroll
        for (int i = 0; i < SPT; i++)
            nnA[i] = sv[i] ? NN[sj[i] * SITES + s1 + scol[i]] : 0;
    }
    __syncthreads();

    const int wave_mt0 = (wave / NWN) * MT_W;
    const int wave_nt0 = (wave % NWN) * NT_W;
    const int o_g      = (wave_mt0 * 16) / NGRP;
    const float bo     = bias[o_g] * LOG2E;

    float y0 = 0.f, y1 = 0.f, y2 = 0.f;   // FUSED accumulators

#pragma unroll 1
    for (int c = 0; c < CHUNKS; c++) {
        const int cur = c & 1;
        const __bf16* xh = xh_lds + cur * BUF;
        const __bf16* xl = xl_lds + cur * BUF;

        // --- (1) compute chunk c from buffer cur (bias in acc init) ---------
        f32x4 acc[MT_W][NT_W];
        const f32x4 binit = {bo, bo, bo, bo};
#pragma unroll
        for (int mt = 0; mt < MT_W; mt++)
#pragma unroll
            for (int nt = 0; nt < NT_W; nt++) acc[mt][nt] = binit;

#pragma unroll
        for (int kt = 0; kt < KT; kt++) {
            const int koff = kt * 32 + quad * 8;
            // B-frag offset clamp: for koff >= KEXT the A-weights are zero,
            // so read quad-0's (in-bounds) data instead - contributes 0.
            const int koffb = (KEXT < KPAD && koff > KEXT - 8) ? (KEXT - 8) : koff;
            bf16x8 ah[MT_W], al[MT_W], bh[NT_W], bl[NT_W];
#pragma unroll
            for (int mt = 0; mt < MT_W; mt++) {
                int row = (wave_mt0 + mt) * 16 + m16;
                ah[mt] = *(const bf16x8*)(Wh + (size_t)row * KPAD + koff);
                al[mt] = *(const bf16x8*)(Wl + (size_t)row * KPAD + koff);
            }
#pragma unroll
            for (int nt = 0; nt < NT_W; nt++) {
                int cbase = ((wave_nt0 + nt) * 16 + m16) * KSTR + koffb;
                bh[nt] = *(const bf16x8*)(xh + cbase);
                bl[nt] = *(const bf16x8*)(xl + cbase);
            }
            // product-major: independent MFMAs between same-acc reuse
#pragma unroll
            for (int mt = 0; mt < MT_W; mt++)
#pragma unroll
                for (int nt = 0; nt < NT_W; nt++)
                    acc[mt][nt] = __builtin_amdgcn_mfma_f32_16x16x32_bf16(
                        ah[mt], bh[nt], acc[mt][nt], 0, 0, 0);
#pragma unroll
            for (int mt = 0; mt < MT_W; mt++)
#pragma unroll
                for (int nt = 0; nt < NT_W; nt++)
                    acc[mt][nt] = __builtin_amdgcn_mfma_f32_16x16x32_bf16(
                        al[mt], bh[nt], acc[mt][nt], 0, 0, 0);
#pragma unroll
            for (int mt = 0; mt < MT_W; mt++)
#pragma unroll
                for (int nt = 0; nt < NT_W; nt++)
                    acc[mt][nt] = __builtin_amdgcn_mfma_f32_16x16x32_bf16(
                        ah[mt], bl[nt], acc[mt][nt], 0, 0, 0);
        }

        // --- (2) epilogue: log2-domain softplus + group mean ----------------
        const int s0c = s0base + c * CT;
#pragma unroll
        for (int nt = 0; nt < NT_W; nt++) {
            float s = 0.f;
#pragma unroll
            for (int mt = 0; mt < MT_W; mt++)
#pragma unroll
                for (int r = 0; r < 4; r++) {
                    float h = acc[mt][nt][r];
                    s += fmaxf(h, 0.f) + __log2f(1.f + exp2f(-fabsf(h)));
                }
            s += __shfl_xor(s, 16);
            s += __shfl_xor(s, 32);
            if (quad == 0) {
                int site = s0c + (wave_nt0 + nt) * 16 + m16;
                if constexpr (FUSED) {
                    y0 = fmaf(SWp[site],             s, y0);
                    y1 = fmaf(SWp[SITES + site],     s, y1);
                    y2 = fmaf(SWp[2 * SITES + site], s, y2);
                } else {
                    out[((size_t)(b * SITES + site)) * NCTOT + o_g] = s * SPSCALE;
                }
            }
        }

        // --- (3) stage chunk c+1 into buffer cur^1 (late, v13 ordering) -----
        if (c + 1 < CHUNKS) {
            __bf16* dh = xh_lds + (cur ^ 1) * BUF;
            __bf16* dl = xl_lds + (cur ^ 1) * BUF;
#pragma unroll
            for (int i = 0; i < SPT; i++) if (sv[i])
                stage_site(i, nnA[i], dh, dl);
            if (c + 2 < CHUNKS) {
                const int s2 = s0base + (c + 2) * CT;
#pragma unroll
                for (int i = 0; i < SPT; i++)
                    nnA[i] = sv[i] ? NN[sj[i] * SITES + s2 + scol[i]] : 0;
            }
        }
        __syncthreads();
    }

    // --- FUSED: block-reduce y[3] -> per-block partial ----------------------
    if constexpr (FUSED) {
        float* red = (float*)xh_lds;   // last loop iter ended with a barrier
        red[tid] = y0;
        red[NTHR + tid] = y1;
        red[2 * NTHR + tid] = y2;
        __syncthreads();
        for (int st = NTHR / 2; st > 0; st >>= 1) {
            if (tid < st) {
                red[tid] += red[tid + st];
                red[NTHR + tid] += red[NTHR + tid + st];
                red[2 * NTHR + tid] += red[2 * NTHR + tid + st];
            }
            __syncthreads();
        }
        if (tid < 3) partial[bid * 3 + tid] = red[tid * NTHR];
    }
}

// ---------------------------------------------------------------------------
// final_sum: out[b,d] = sum over the batch's 8 octet blocks (deterministic).
// ---------------------------------------------------------------------------
__global__ __launch_bounds__(256) void final_sum(
    const float* __restrict__ partial, float* __restrict__ out)
{
    int t = threadIdx.x;
    if (t < BATCH * 3) {
        int b = t / 3, d = t - b * 3;
        float s = 0.f;
        for (int o = 0; o < 8; o++) s += partial[(b * 8 + o) * 3 + d];
        out[t] = s;
    }
}

// ---------------------------------------------------------------------------
extern "C" void kernel_launch(void* const* d_in, const int* in_sizes, int n_in,
                              void* d_out, int out_size, void* d_ws, size_t ws_size,
                              hipStream_t stream)
{
    const float* InStates = (const float*)d_in[0];
    const float* Psi0     = (const float*)d_in[1];
    const float* bias0    = (const float*)d_in[2];
    const float* Psi1     = (const float*)d_in[3];
    const float* bias1    = (const float*)d_in[4];
    const float* Psi2     = (const float*)d_in[5];
    const float* bias2    = (const float*)d_in[6];
    const float* wtVC     = (const float*)d_in[7];
    const float* ShellW   = (const float*)d_in[8];
    const float* gdiags   = (const float*)d_in[9];
    const int*   GnnPerms = (const int*)d_in[10];
    const int*   NNSites  = (const int*)d_in[11];
    const int*   S2Sh     = (const int*)d_in[12];

    float*  ws   = (float*)d_ws;
    float*  Avc  = ws + OFF_AVC;
    __bf16* U    = (__bf16*)(ws + OFF_U);
    float*  A0   = ws + OFF_A0;      // (B,S,8) channel-last
    float*  SW   = ws + OFF_SW;      // [3][4096], aliases A0 (dead after L1)
    float*  A1   = ws + OFF_A1;      // (B,S,8) channel-last
    float*  PART = ws + OFF_PART;    // (512,3)

    float* out = (float*)d_out;      // (64,3) f32

    hipMemsetAsync(Avc, 0, 64 * sizeof(float), stream);
    precompute_kernel<<<272, 256, 0, stream>>>(Psi0, Psi1, Psi2, wtVC, gdiags,
                                               GnnPerms, ws);

    constexpr int CHUNKS = 8;
    constexpr int NBLK   = BATCH * (SITES / 64) / CHUNKS;   // 512 blocks

    // L0: K=13 pad 32, KEXT=32 (padded in LDS), KSTR=40
    layer_mfma<1, 8, 64, 32, 32, 40, 8, 1, CHUNKS, 0><<<NBLK, 512, 0, stream>>>(
        InStates, U + UW0H, U + UW0L, bias0, NNSites, nullptr, nullptr, A0);
    // L1: K=104 pad 128 (weights), KEXT=104 in LDS, KSTR=104
    layer_mfma<8, 8, 64, 128, 104, 104, 8, 1, CHUNKS, 0><<<NBLK, 512, 0, stream>>>(
        A0, U + UW1H, U + UW1L, bias1, NNSites, nullptr, nullptr, A1);

    // SW build (stream-ordered after L1: A0 region is dead)
    hipMemsetAsync(SW, 0, 3 * SITES * sizeof(float), stream);
    build_sw<<<(NGB * SITES + 255) / 256, 256, 0, stream>>>(
        Avc, NNSites, S2Sh, ShellW, SW);

    // L2: 256 thr unified (v19 form), KEXT=104 -> 3 blocks/CU; fused SW tail
    layer_mfma<8, 1, 64, 128, 104, 104, 4, 4, CHUNKS, 1><<<NBLK, 256, 0, stream>>>(
        A1, U + UW2H, U + UW2L, bias2, NNSites, SW, PART, nullptr);

    final_sum<<<1, 256, 0, stream>>>(PART, out);
}

// Round 12
// 310.212 us; speedup vs baseline: 1.0752x; 1.0003x over previous
//
#include <hip/hip_runtime.h>
#include <hip/hip_bf16.h>

// Problem constants (SymNetDP): B=64, S=4096, NGB=13, NG=48, DIM=3, NCH={8,8,1}
#define BATCH 64
#define SITES 4096
#define NGB 13
#define NGRP 48
#define SDIM 3

#define LOG2E 1.44269504f
#define SPSCALE 0.014440236f   // ln2/48: converts log2-domain softplus sum

typedef __bf16 bf16x8 __attribute__((ext_vector_type(8)));
typedef float  f32x4  __attribute__((ext_vector_type(4)));

// ---------------------------------------------------------------------------
// Workspace layout:
//   Avc  : 39 f32 (pad 64)                      @ float 0
//   U    : bf16 region, 135168 elems            @ float 64
//     W0H [384][32] 12288 | W0L @12288 | W1H [384][128] @24576 (49152) |
//     W1L @73728 | W2H [48][128] @122880 (6144) | W2L @129024
//   A0   : (B,S,16) bf16 INTERLEAVED hi|lo      @ float 67648 (8 MB)
//   SW   : [3][4096] f32, ALIASES A0 (A0 dead once L1 done)
//   A1   : (B,S,16) bf16 interleaved            @ float 2164800
// Activation record: site-contiguous 32 B = h0..h7 l0..l7 (bf16). One cache
// line per gather (like f32), zero cvt at stage time (split done at write).
// K-packing for NCIN=8 layers: k = j*8 + c.
//
// v22 = v21 + (a) interleaved hi/lo bf16 activations, (b) atomic tail.
// (a) v16 showed split-at-write removes staging cvt VALU but separate H/L
//     arrays doubled gather lines (FETCH 42->49MB) and net-lost. One 32B
//     record keeps 1 line/site AND zero staging cvt. Bit-identical split.
// (b) L2's FUSED blocks atomicAdd partials into d_out (zeroed at capture
//     start); final_sum kernel + gap deleted.
// ---------------------------------------------------------------------------
#define OFF_AVC  0
#define OFF_U    64
#define OFF_A0   67648
#define OFF_SW   67648
#define OFF_A1   2164800
#define UW0H 0
#define UW0L 12288
#define UW1H 24576
#define UW1L 73728
#define UW2H 122880
#define UW2L 129024

// ---------------------------------------------------------------------------
// Precompute: rotated weights scaled by log2e, bf16 hi/lo split,
// [row=o*48+g][KPAD] with k=j*8+c packing for K=104 layers (k=j for L0);
// plus Avc (true units - vector channel is linear, no softplus).
// ---------------------------------------------------------------------------
__global__ __launch_bounds__(256) void precompute_kernel(
    const float* __restrict__ Psi0, const float* __restrict__ Psi1,
    const float* __restrict__ Psi2, const float* __restrict__ wtVC,
    const float* __restrict__ gdiags, const int* __restrict__ perms,
    float* __restrict__ ws)
{
    float*  Avc = ws + OFF_AVC;
    __bf16* U   = (__bf16*)(ws + OFF_U);
    int t = blockIdx.x * 256 + threadIdx.x;
    if (t < 12288) {                       // W0: [384][32], k=j
        int k = t & 31, row = t >> 5;
        int o = row / NGRP, g = row - o * NGRP;
        float w = (k < NGB) ? Psi0[o * NGB + perms[g * NGB + k]] * LOG2E : 0.f;
        __bf16 hi = (__bf16)w;
        U[UW0H + t] = hi;
        U[UW0L + t] = (__bf16)(w - (float)hi);
    } else if (t < 61440) {                // W1: [384][128], k=j*8+c
        int u = t - 12288;
        int k = u & 127, row = u >> 7;
        int o = row / NGRP, g = row - o * NGRP;
        float w = 0.f;
        if (k < 104) { int j = k >> 3, c = k & 7;
                       w = Psi1[(o * 8 + c) * NGB + perms[g * NGB + j]] * LOG2E; }
        __bf16 hi = (__bf16)w;
        U[UW1H + u] = hi;
        U[UW1L + u] = (__bf16)(w - (float)hi);
    } else if (t < 67584) {                // W2: [48][128], k=j*8+c
        int u = t - 61440;
        int k = u & 127, g = u >> 7;
        float w = 0.f;
        if (k < 104) { int j = k >> 3, c = k & 7;
                       w = Psi2[c * NGB + perms[g * NGB + j]] * LOG2E; }
        __bf16 hi = (__bf16)w;
        U[UW2H + u] = hi;
        U[UW2L + u] = (__bf16)(w - (float)hi);
    } else if (t < 67584 + 39 * NGRP) {    // Avc (true units)
        int t2 = t - 67584;
        int g = t2 % NGRP, u = t2 / NGRP;
        int d = u / NGB, n = u % NGB;
        const int row = g * SDIM + d;
        float s = 0.f;
        for (int k = 0; k < NGRP * SDIM; k++) {
            int g2 = k / SDIM, d2 = k - g2 * SDIM;
            float p = wtVC[d2 * NGB + perms[g2 * NGB + n]];
            s = fmaf(gdiags[row * (NGRP * SDIM) + k], p, s);
        }
        atomicAdd(&Avc[u], s * (1.f / 48.f));
    }
}

// ---------------------------------------------------------------------------
// build_sw: SW[d][t] = sum over edges (n,s) with NN[n,s]=t of
//   Avc[d,n] * ShellW[S2Sh[s]] * (ln2/48) / SITES.
// ---------------------------------------------------------------------------
__global__ __launch_bounds__(256) void build_sw(
    const float* __restrict__ Avc, const int* __restrict__ NN,
    const int* __restrict__ s2sh, const float* __restrict__ shellw,
    float* __restrict__ SW)
{
    int e = blockIdx.x * 256 + threadIdx.x;    // e = n*SITES + s
    if (e < NGB * SITES) {
        int n = e / SITES, s = e - n * SITES;
        float wgt = shellw[s2sh[s]] * (SPSCALE / (float)SITES);
        int t = NN[e];
        atomicAdd(&SW[t],             Avc[n] * wgt);
        atomicAdd(&SW[SITES + t],     Avc[NGB + n] * wgt);
        atomicAdd(&SW[2 * SITES + t], Avc[2 * NGB + n] * wgt);
    }
}

// ---------------------------------------------------------------------------
// MFMA gconv layer (bf16x3 split), v19 structure + KEXT diet + interleaved
// hi/lo activations.
// Persistent-lite: per iteration compute chunk c from buffer c&1, epilogue,
// THEN gather+ds_write chunk c+1 (indices prefetched). Product-major MFMA.
// NCIN==8 staging: one 32B record = {8 bf16 hi, 8 bf16 lo}; two b128 LDS
// writes, zero cvt. KEXT clamp as v21.
// Epilogue: log2-domain softplus, bias in acc init; output written as
// interleaved hi/lo (split here, bit-identical to splitting at stage time).
// FUSED (L2): y[3] += SW[d][site]*sraw; block reduce -> atomicAdd(out).
// ---------------------------------------------------------------------------
template<int NCIN, int NCTOT, int CT, int KPAD, int KEXT, int KSTR,
         int NWAVES, int NWN, int CHUNKS, int FUSED>
__global__ __launch_bounds__(NWAVES * 64) void layer_mfma(
    const float*  __restrict__ prevF,  // (B,S) f32 (NCIN==1)
    const __bf16* __restrict__ prevB,  // (B,S,16) interleaved (NCIN==8)
    const __bf16* __restrict__ Wh,     // [NCTOT*48][KPAD]
    const __bf16* __restrict__ Wl,
    const float*  __restrict__ bias,   // (NCTOT,)
    const int*    __restrict__ NN,     // (13, S)
    const float*  __restrict__ SWp,    // [3][SITES] (FUSED only)
    float* __restrict__ outAcc,        // (64,3) atomic target (FUSED only)
    __bf16* __restrict__ outB)         // (B,S,16) interleaved (!FUSED)
{
    constexpr int NTHR   = NWAVES * 64;
    constexpr int M      = NCTOT * NGRP;
    constexpr int MTILES = M / 16, NTILES = CT / 16;
    constexpr int NWM    = NWAVES / NWN;
    constexpr int MT_W   = MTILES / NWM, NT_W = NTILES / NWN;
    constexpr int KT     = KPAD / 32;
    constexpr int GS     = NGB * CT;              // gathered sites per chunk
    constexpr int SPT    = (GS + NTHR - 1) / NTHR;
    constexpr int CPB    = SITES / CT;            // chunks per batch
    constexpr int BUF    = CT * KSTR;             // halfwords per LDS buffer
    constexpr int BPB    = CPB / CHUNKS;          // blocks per batch

    static_assert(MT_W * 16 == NGRP, "wave covers exactly one o");
    static_assert(NWM * MT_W == MTILES && NWN * NT_W == NTILES, "");
    static_assert((KPAD & 31) == 0 && (KSTR & 7) == 0, "");
    static_assert(KEXT <= KPAD && (KEXT & 7) == 0 && KSTR >= KEXT, "");
    static_assert(CPB % CHUNKS == 0, "block stays within one batch");

    __shared__ __bf16 xh_lds[2 * BUF];
    __shared__ __bf16 xl_lds[2 * BUF];

    const int tid  = threadIdx.x;
    const int wave = tid >> 6, lane = tid & 63;
    const int m16  = lane & 15, quad = lane >> 4;

    const int bid    = blockIdx.x;
    const int b      = bid / BPB;
    const int octet  = bid % BPB;
    const int s0base = octet * (CHUNKS * CT);

    // --- per-thread staged-site slots (static decomposition) ----------------
    int sj[SPT], scol[SPT];
    bool sv[SPT];
#pragma unroll
    for (int i = 0; i < SPT; i++) {
        int site = tid + i * NTHR;
        sv[i] = (site < GS);
        int ss = sv[i] ? site : 0;
        sj[i] = ss / CT;
        scol[i] = ss % CT;
    }

    // staging of one site: interleaved record -> two b128 LDS writes (no cvt)
    auto stage_site = [&](int i, int nn, __bf16* dh, __bf16* dl) {
        if constexpr (NCIN == 1) {
            float v = prevF[(size_t)b * SITES + nn];
            __bf16 hi = (__bf16)v;
            dh[scol[i] * KSTR + sj[i]] = hi;
            dl[scol[i] * KSTR + sj[i]] = (__bf16)(v - (float)hi);
        } else {
            const bf16x8* p = (const bf16x8*)(prevB + ((size_t)(b * SITES + nn)) * 16);
            bf16x8 hv = p[0], lv = p[1];
            *(bf16x8*)(dh + scol[i] * KSTR + sj[i] * 8) = hv;
            *(bf16x8*)(dl + scol[i] * KSTR + sj[i] * 8) = lv;
        }
    };

    // --- zero K-pad (NCIN==1 only; NCIN==8 has no pad region: KEXT=104) -----
    if constexpr (NCIN == 1) {
        for (int e = tid; e < 2 * CT * (KPAD - NGB); e += NTHR) {
            int buf = e / (CT * (KPAD - NGB));
            int r   = e % (CT * (KPAD - NGB));
            int col = r / (KPAD - NGB), p = r % (KPAD - NGB);
            xh_lds[buf * BUF + col * KSTR + NGB + p] = (__bf16)0.f;
            xl_lds[buf * BUF + col * KSTR + NGB + p] = (__bf16)0.f;
        }
    }

    // --- prologue: stage chunk 0 into buffer 0; prefetch NN for chunk 1 -----
    int nnA[SPT];
#pragma unroll
    for (int i = 0; i < SPT; i++) if (sv[i]) {
        int nn = NN[sj[i] * SITES + s0base + scol[i]];
        stage_site(i, nn, xh_lds, xl_lds);
    }
    if (CHUNKS > 1) {
        const int s1 = s0base + CT;
#pragma unroll
        for (int i = 0; i < SPT; i++)
            nnA[i] = sv[i] ? NN[sj[i] * SITES + s1 + scol[i]] : 0;
    }
    __syncthreads();

    const int wave_mt0 = (wave / NWN) * MT_W;
    const int wave_nt0 = (wave % NWN) * NT_W;
    const int o_g      = (wave_mt0 * 16) / NGRP;
    const float bo     = bias[o_g] * LOG2E;

    float y0 = 0.f, y1 = 0.f, y2 = 0.f;   // FUSED accumulators

#pragma unroll 1
    for (int c = 0; c < CHUNKS; c++) {
        const int cur = c & 1;
        const __bf16* xh = xh_lds + cur * BUF;
        const __bf16* xl = xl_lds + cur * BUF;

        // --- (1) compute chunk c from buffer cur (bias in acc init) ---------
        f32x4 acc[MT_W][NT_W];
        const f32x4 binit = {bo, bo, bo, bo};
#pragma unroll
        for (int mt = 0; mt < MT_W; mt++)
#pragma unroll
            for (int nt = 0; nt < NT_W; nt++) acc[mt][nt] = binit;

#pragma unroll
        for (int kt = 0; kt < KT; kt++) {
            const int koff = kt * 32 + quad * 8;
            // B-frag clamp: for koff >= KEXT the A-weights are zero, so read
            // quad-0's (in-bounds) data instead - contributes exactly 0.
            const int koffb = (KEXT < KPAD && koff > KEXT - 8) ? (KEXT - 8) : koff;
            bf16x8 ah[MT_W], al[MT_W], bh[NT_W], bl[NT_W];
#pragma unroll
            for (int mt = 0; mt < MT_W; mt++) {
                int row = (wave_mt0 + mt) * 16 + m16;
                ah[mt] = *(const bf16x8*)(Wh + (size_t)row * KPAD + koff);
                al[mt] = *(const bf16x8*)(Wl + (size_t)row * KPAD + koff);
            }
#pragma unroll
            for (int nt = 0; nt < NT_W; nt++) {
                int cbase = ((wave_nt0 + nt) * 16 + m16) * KSTR + koffb;
                bh[nt] = *(const bf16x8*)(xh + cbase);
                bl[nt] = *(const bf16x8*)(xl + cbase);
            }
            // product-major: independent MFMAs between same-acc reuse
#pragma unroll
            for (int mt = 0; mt < MT_W; mt++)
#pragma unroll
                for (int nt = 0; nt < NT_W; nt++)
                    acc[mt][nt] = __builtin_amdgcn_mfma_f32_16x16x32_bf16(
                        ah[mt], bh[nt], acc[mt][nt], 0, 0, 0);
#pragma unroll
            for (int mt = 0; mt < MT_W; mt++)
#pragma unroll
                for (int nt = 0; nt < NT_W; nt++)
                    acc[mt][nt] = __builtin_amdgcn_mfma_f32_16x16x32_bf16(
                        al[mt], bh[nt], acc[mt][nt], 0, 0, 0);
#pragma unroll
            for (int mt = 0; mt < MT_W; mt++)
#pragma unroll
                for (int nt = 0; nt < NT_W; nt++)
                    acc[mt][nt] = __builtin_amdgcn_mfma_f32_16x16x32_bf16(
                        ah[mt], bl[nt], acc[mt][nt], 0, 0, 0);
        }

        // --- (2) epilogue: log2-domain softplus + group mean ----------------
        const int s0c = s0base + c * CT;
#pragma unroll
        for (int nt = 0; nt < NT_W; nt++) {
            float s = 0.f;
#pragma unroll
            for (int mt = 0; mt < MT_W; mt++)
#pragma unroll
                for (int r = 0; r < 4; r++) {
                    float h = acc[mt][nt][r];
                    s += fmaxf(h, 0.f) + __log2f(1.f + exp2f(-fabsf(h)));
                }
            s += __shfl_xor(s, 16);
            s += __shfl_xor(s, 32);
            if (quad == 0) {
                int site = s0c + (wave_nt0 + nt) * 16 + m16;
                if constexpr (FUSED) {
                    y0 = fmaf(SWp[site],             s, y0);
                    y1 = fmaf(SWp[SITES + site],     s, y1);
                    y2 = fmaf(SWp[2 * SITES + site], s, y2);
                } else {
                    float sv2 = s * SPSCALE;
                    __bf16 hi = (__bf16)sv2;
                    size_t idx = ((size_t)(b * SITES + site)) * 16;
                    outB[idx + o_g]     = hi;
                    outB[idx + 8 + o_g] = (__bf16)(sv2 - (float)hi);
                }
            }
        }

        // --- (3) stage chunk c+1 into buffer cur^1 (late, v13 ordering) -----
        if (c + 1 < CHUNKS) {
            __bf16* dh = xh_lds + (cur ^ 1) * BUF;
            __bf16* dl = xl_lds + (cur ^ 1) * BUF;
#pragma unroll
            for (int i = 0; i < SPT; i++) if (sv[i])
                stage_site(i, nnA[i], dh, dl);
            if (c + 2 < CHUNKS) {
                const int s2 = s0base + (c + 2) * CT;
#pragma unroll
                for (int i = 0; i < SPT; i++)
                    nnA[i] = sv[i] ? NN[sj[i] * SITES + s2 + scol[i]] : 0;
            }
        }
        __syncthreads();
    }

    // --- FUSED: block-reduce y[3] -> atomicAdd into out ---------------------
    if constexpr (FUSED) {
        float* red = (float*)xh_lds;   // last loop iter ended with a barrier
        red[tid] = y0;
        red[NTHR + tid] = y1;
        red[2 * NTHR + tid] = y2;
        __syncthreads();
        for (int st = NTHR / 2; st > 0; st >>= 1) {
            if (tid < st) {
                red[tid] += red[tid + st];
                red[NTHR + tid] += red[NTHR + tid + st];
                red[2 * NTHR + tid] += red[2 * NTHR + tid + st];
            }
            __syncthreads();
        }
        if (tid < 3) atomicAdd(&outAcc[b * 3 + tid], red[tid * NTHR]);
    }
}

// ---------------------------------------------------------------------------
extern "C" void kernel_launch(void* const* d_in, const int* in_sizes, int n_in,
                              void* d_out, int out_size, void* d_ws, size_t ws_size,
                              hipStream_t stream)
{
    const float* InStates = (const float*)d_in[0];
    const float* Psi0     = (const float*)d_in[1];
    const float* bias0    = (const float*)d_in[2];
    const float* Psi1     = (const float*)d_in[3];
    const float* bias1    = (const float*)d_in[4];
    const float* Psi2     = (const float*)d_in[5];
    const float* bias2    = (const float*)d_in[6];
    const float* wtVC     = (const float*)d_in[7];
    const float* ShellW   = (const float*)d_in[8];
    const float* gdiags   = (const float*)d_in[9];
    const int*   GnnPerms = (const int*)d_in[10];
    const int*   NNSites  = (const int*)d_in[11];
    const int*   S2Sh     = (const int*)d_in[12];

    float*  ws   = (float*)d_ws;
    float*  Avc  = ws + OFF_AVC;
    __bf16* U    = (__bf16*)(ws + OFF_U);
    __bf16* A0   = (__bf16*)(ws + OFF_A0);   // (B,S,16) interleaved
    float*  SW   = ws + OFF_SW;              // [3][4096], aliases A0
    __bf16* A1   = (__bf16*)(ws + OFF_A1);   // (B,S,16) interleaved

    float* out = (float*)d_out;      // (64,3) f32

    hipMemsetAsync(Avc, 0, 64 * sizeof(float), stream);
    hipMemsetAsync(out, 0, BATCH * 3 * sizeof(float), stream);
    precompute_kernel<<<272, 256, 0, stream>>>(Psi0, Psi1, Psi2, wtVC, gdiags,
                                               GnnPerms, ws);

    constexpr int CHUNKS = 8;
    constexpr int NBLK   = BATCH * (SITES / 64) / CHUNKS;   // 512 blocks

    // L0: K=13 pad 32, KEXT=32 (padded in LDS), KSTR=40; f32 in, bf16x2 out
    layer_mfma<1, 8, 64, 32, 32, 40, 8, 1, CHUNKS, 0><<<NBLK, 512, 0, stream>>>(
        InStates, nullptr, U + UW0H, U + UW0L, bias0, NNSites,
        nullptr, nullptr, A0);
    // L1: K=104 pad 128 (weights), KEXT=104 in LDS, KSTR=104
    layer_mfma<8, 8, 64, 128, 104, 104, 8, 1, CHUNKS, 0><<<NBLK, 512, 0, stream>>>(
        nullptr, A0, U + UW1H, U + UW1L, bias1, NNSites,
        nullptr, nullptr, A1);

    // SW build (stream-ordered after L1: A0 region is dead)
    hipMemsetAsync(SW, 0, 3 * SITES * sizeof(float), stream);
    build_sw<<<(NGB * SITES + 255) / 256, 256, 0, stream>>>(
        Avc, NNSites, S2Sh, ShellW, SW);

    // L2: 256 thr unified, KEXT=104; fused SW tail -> atomicAdd(out)
    layer_mfma<8, 1, 64, 128, 104, 104, 4, 4, CHUNKS, 1><<<NBLK, 256, 0, stream>>>(
        nullptr, A1, U + UW2H, U + UW2L, bias2, NNSites,
        SW, out, nullptr);
}